// Round 1
// baseline (673.960 us; speedup 1.0000x reference)
//
#include <hip/hip_runtime.h>

#define N_NODES 50000
#define N_EDGES 600000
#define F 128
#define NRELL 9   // 8 relations + self-loop folded in as r=8

// ---------- ws layout ----------
#define WT_BYTES   (9*128*128*2)                  // bf16 W transposed [r][o][i]
#define GATE_OFF   WT_BYTES
#define GATE_BYTES (8*N_NODES*4)                  // sigmoid(h . gw_r) per (r,node)
#define HREL_OFF   (WT_BYTES + GATE_BYTES)        // 1894912, 256-aligned
#define HREL_BYTES (9ll*N_NODES*128*2)            // bf16 h_rel [r][n][o]
#define WS_NEED    ((size_t)HREL_OFF + (size_t)HREL_BYTES)

typedef __attribute__((ext_vector_type(8))) short short8;
typedef __attribute__((ext_vector_type(4))) float floatx4;

__device__ inline unsigned short f32_to_bf16(float f) {
    unsigned u = __float_as_uint(f);
    unsigned r = u + 0x7fff + ((u >> 16) & 1);
    return (unsigned short)(r >> 16);
}
__device__ inline float bf16_to_f32(unsigned short s) {
    return __uint_as_float(((unsigned)s) << 16);
}
__device__ inline float sigmoidf(float x) { return 1.f / (1.f + __expf(-x)); }

// ---------- kernel 1: repack weights (+loop_weight as r=8) to bf16, transposed [r][o][i] ----------
__global__ void k_prep_w(const float* __restrict__ W, const float* __restrict__ LW,
                         unsigned short* __restrict__ Wt) {
    int idx = blockIdx.x * 256 + threadIdx.x;      // 9*16384 = 147456 total
    if (idx >= 9 * 128 * 128) return;
    int r = idx >> 14;
    int rem = idx & 16383;
    int i = rem >> 7, o = rem & 127;
    float v = (r < 8) ? W[(r << 14) + (i << 7) + o] : LW[(i << 7) + o];
    Wt[(r << 14) + (o << 7) + i] = f32_to_bf16(v);
}

// ---------- kernel 2: gate[r][n] = sigmoid(h[n] . gw[r]) ----------
__global__ void k_gate(const float* __restrict__ h, const float* __restrict__ gw,
                       float* __restrict__ gate) {
    int wave = threadIdx.x >> 6, lane = threadIdx.x & 63;
    int n = blockIdx.x * 4 + wave;
    if (n >= N_NODES) return;
    float2 hv = *(const float2*)(h + (size_t)n * F + lane * 2);
    #pragma unroll
    for (int r = 0; r < 8; ++r) {
        float2 wv = *(const float2*)(gw + r * F + lane * 2);
        float p = hv.x * wv.x + hv.y * wv.y;
        #pragma unroll
        for (int off = 32; off; off >>= 1) p += __shfl_xor(p, off);
        if (lane == 0) gate[r * N_NODES + n] = sigmoidf(p);
    }
}

// ---------- kernel 3: h_rel[r][n][o] = (h @ W_r) in bf16 via MFMA ----------
#define LDH 136
#define LDW 136
__global__ __launch_bounds__(256) void k_hrel(const float* __restrict__ h,
                                              const unsigned short* __restrict__ Wt,
                                              unsigned short* __restrict__ hrel) {
    __shared__ unsigned short hA[64 * LDH];
    __shared__ unsigned short wB[128 * LDW];
    int tid = threadIdx.x;
    int nb = blockIdx.x * 64;

    // stage 64x128 h tile as bf16
    #pragma unroll
    for (int it = 0; it < 8; ++it) {
        int idx = it * 1024 + tid * 4;
        int row = idx >> 7, col = idx & 127;
        int node = nb + row;
        float4 v;
        if (node < N_NODES) v = *(const float4*)(h + (size_t)node * F + col);
        else                v = make_float4(0.f, 0.f, 0.f, 0.f);
        ushort4 b;
        b.x = f32_to_bf16(v.x); b.y = f32_to_bf16(v.y);
        b.z = f32_to_bf16(v.z); b.w = f32_to_bf16(v.w);
        *(ushort4*)(&hA[row * LDH + col]) = b;
    }

    int wave = tid >> 6, lane = tid & 63;
    int lrow = lane & 15, quad = lane >> 4;
    const unsigned short* aptr = &hA[(wave * 16 + lrow) * LDH + quad * 8];

    for (int r = 0; r < NRELL; ++r) {
        __syncthreads();   // hA ready / previous wB reads done
        // stage W_r^T (o-major, k contiguous) 128x128 bf16
        #pragma unroll
        for (int it = 0; it < 8; ++it) {
            int idx = it * 2048 + tid * 8;
            int o = idx >> 7, i = idx & 127;
            *(uint4*)(&wB[o * LDW + i]) = *(const uint4*)(Wt + (r << 14) + idx);
        }
        __syncthreads();

        floatx4 acc[8];
        #pragma unroll
        for (int nt = 0; nt < 8; ++nt) acc[nt] = (floatx4){0.f, 0.f, 0.f, 0.f};
        #pragma unroll
        for (int kt = 0; kt < 4; ++kt) {
            short8 a = *(const short8*)(aptr + kt * 32);
            #pragma unroll
            for (int nt = 0; nt < 8; ++nt) {
                short8 b = *(const short8*)(&wB[(nt * 16 + lrow) * LDW + kt * 32 + quad * 8]);
                acc[nt] = __builtin_amdgcn_mfma_f32_16x16x32_bf16(a, b, acc[nt], 0, 0, 0);
            }
        }
        unsigned short* dstp = hrel + (size_t)r * N_NODES * F;
        #pragma unroll
        for (int nt = 0; nt < 8; ++nt) {
            #pragma unroll
            for (int g = 0; g < 4; ++g) {
                int node = nb + wave * 16 + quad * 4 + g;
                if (node < N_NODES)
                    dstp[(size_t)node * F + nt * 16 + lrow] = f32_to_bf16(acc[nt][g]);
            }
        }
    }
}

// ---------- kernel 4: edge gather + scale + atomic scatter ----------
__global__ void k_edges(const unsigned short* __restrict__ hrel,
                        const float* __restrict__ gate,
                        const float* __restrict__ norm,
                        const int* __restrict__ src, const int* __restrict__ dst,
                        const int* __restrict__ rel,
                        float* __restrict__ out) {
    int wave = threadIdx.x >> 6, lane = threadIdx.x & 63;
    int e = blockIdx.x * 4 + wave;
    if (e >= N_EDGES) return;
    int s = src[e], d = dst[e], r = rel[e];
    float scale = norm[e] * gate[r * N_NODES + s];
    unsigned int m = *(const unsigned int*)(hrel + ((size_t)r * N_NODES + s) * F + lane * 2);
    float v0 = bf16_to_f32((unsigned short)(m & 0xffffu)) * scale;
    float v1 = bf16_to_f32((unsigned short)(m >> 16)) * scale;
    float* op = out + (size_t)d * F + lane * 2;
    unsafeAtomicAdd(op, v0);
    unsafeAtomicAdd(op + 1, v1);
}

// ---------- kernel 5: out = relu(agg + bias + h_rel[8]) ----------
__global__ void k_final(float* __restrict__ out, const float* __restrict__ bias,
                        const unsigned short* __restrict__ hrel8) {
    int idx = blockIdx.x * 256 + threadIdx.x;    // N_NODES*32 float4 groups
    if (idx >= N_NODES * 32) return;
    int node = idx >> 5, c4 = (idx & 31) * 4;
    float4 a = *(float4*)(out + (size_t)node * F + c4);
    float4 b = *(const float4*)(bias + c4);
    ushort4 l = *(const ushort4*)(hrel8 + (size_t)node * F + c4);
    float o0 = fmaxf(a.x + b.x + bf16_to_f32(l.x), 0.f);
    float o1 = fmaxf(a.y + b.y + bf16_to_f32(l.y), 0.f);
    float o2 = fmaxf(a.z + b.z + bf16_to_f32(l.z), 0.f);
    float o3 = fmaxf(a.w + b.w + bf16_to_f32(l.w), 0.f);
    *(float4*)(out + (size_t)node * F + c4) = make_float4(o0, o1, o2, o3);
}

// ---------- ws-free fallback: per-edge on-the-fly matvec ----------
__global__ void k_edges_fb(const float* __restrict__ h, const float* __restrict__ W,
                           const float* __restrict__ gw, const float* __restrict__ norm,
                           const int* __restrict__ src, const int* __restrict__ dst,
                           const int* __restrict__ rel, float* __restrict__ out) {
    int wave = threadIdx.x >> 6, lane = threadIdx.x & 63;
    int e = blockIdx.x * 4 + wave;
    if (e >= N_EDGES) return;
    int s = src[e], d = dst[e], r = rel[e];
    float2 hv = *(const float2*)(h + (size_t)s * F + lane * 2);
    float2 gv = *(const float2*)(gw + r * F + lane * 2);
    float p = hv.x * gv.x + hv.y * gv.y;
    #pragma unroll
    for (int off = 32; off; off >>= 1) p += __shfl_xor(p, off);
    float scale = norm[e] * sigmoidf(p);
    const float* wr = W + ((size_t)r << 14);
    float a0 = 0.f, a1 = 0.f;
    for (int i2 = 0; i2 < 64; ++i2) {
        float x0 = __shfl(hv.x, i2), x1 = __shfl(hv.y, i2);
        a0 += x0 * wr[(2 * i2) * F + lane]     + x1 * wr[(2 * i2 + 1) * F + lane];
        a1 += x0 * wr[(2 * i2) * F + 64 + lane] + x1 * wr[(2 * i2 + 1) * F + 64 + lane];
    }
    unsafeAtomicAdd(out + (size_t)d * F + lane,      a0 * scale);
    unsafeAtomicAdd(out + (size_t)d * F + 64 + lane, a1 * scale);
}

__global__ void k_final_fb(const float* __restrict__ h, const float* __restrict__ LW,
                           const float* __restrict__ bias, float* __restrict__ out) {
    int wave = threadIdx.x >> 6, lane = threadIdx.x & 63;
    int n = blockIdx.x * 4 + wave;
    if (n >= N_NODES) return;
    float2 hv = *(const float2*)(h + (size_t)n * F + lane * 2);
    float a0 = 0.f, a1 = 0.f;
    for (int i2 = 0; i2 < 64; ++i2) {
        float x0 = __shfl(hv.x, i2), x1 = __shfl(hv.y, i2);
        a0 += x0 * LW[(2 * i2) * F + lane]      + x1 * LW[(2 * i2 + 1) * F + lane];
        a1 += x0 * LW[(2 * i2) * F + 64 + lane] + x1 * LW[(2 * i2 + 1) * F + 64 + lane];
    }
    float* op = out + (size_t)n * F;
    op[lane]      = fmaxf(op[lane]      + bias[lane]      + a0, 0.f);
    op[64 + lane] = fmaxf(op[64 + lane] + bias[64 + lane] + a1, 0.f);
}

extern "C" void kernel_launch(void* const* d_in, const int* in_sizes, int n_in,
                              void* d_out, int out_size, void* d_ws, size_t ws_size,
                              hipStream_t stream) {
    const float* h    = (const float*)d_in[0];
    const float* W    = (const float*)d_in[1];
    const float* gw   = (const float*)d_in[2];
    const float* bias = (const float*)d_in[3];
    const float* lw   = (const float*)d_in[4];
    const float* norm = (const float*)d_in[5];
    const int* src    = (const int*)d_in[6];
    const int* dst    = (const int*)d_in[7];
    const int* rel    = (const int*)d_in[8];
    float* out = (float*)d_out;

    hipMemsetAsync(d_out, 0, (size_t)out_size * sizeof(float), stream);

    if (ws_size >= WS_NEED) {
        unsigned short* Wt   = (unsigned short*)d_ws;
        float*          gate = (float*)((char*)d_ws + GATE_OFF);
        unsigned short* hrel = (unsigned short*)((char*)d_ws + HREL_OFF);
        k_prep_w<<<576, 256, 0, stream>>>(W, lw, Wt);
        k_gate<<<12500, 256, 0, stream>>>(h, gw, gate);
        k_hrel<<<782, 256, 0, stream>>>(h, Wt, hrel);
        k_edges<<<150000, 256, 0, stream>>>(hrel, gate, norm, src, dst, rel, out);
        k_final<<<6250, 256, 0, stream>>>(out, bias, hrel + (size_t)8 * N_NODES * F);
    } else {
        // ws too small: compute everything on the fly (slower, still correct)
        k_edges_fb<<<150000, 256, 0, stream>>>(h, W, gw, norm, src, dst, rel, out);
        k_final_fb<<<12500, 256, 0, stream>>>(h, lw, bias, out);
    }
}

// Round 2
// 302.380 us; speedup vs baseline: 2.2289x; 2.2289x over previous
//
#include <hip/hip_runtime.h>

#define N_NODES 50000
#define N_EDGES 600000
#define F 128
#define NRELL 9   // 8 relations + self-loop folded in as r=8
#define NB_SCAN 196  // ceil(50000/256)

// ---------- ws layout (all offsets 256-aligned) ----------
#define WT_OFF     0
#define WT_BYTES   (9*128*128*2)                  // bf16 W transposed [r][o][i]
#define GATE_OFF   294912
#define GATE_BYTES (8*N_NODES*4)
#define HREL_OFF   1894912
#define HREL_BYTES (9ll*N_NODES*128*2)            // bf16 h_rel [r][n][o]
#define CNT_OFF    117094912
#define BASE_OFF   117294912
#define CUR_OFF    117494912
#define BSUM_OFF   117694912
#define SORT_OFF   117695936
#define WS_NEED2   ((size_t)120095936)
#define WS_NEED1   ((size_t)HREL_OFF + (size_t)HREL_BYTES)   // atomic-path minimum

typedef __attribute__((ext_vector_type(8))) short short8;
typedef __attribute__((ext_vector_type(4))) float floatx4;

__device__ inline unsigned short f32_to_bf16(float f) {
    unsigned u = __float_as_uint(f);
    unsigned r = u + 0x7fff + ((u >> 16) & 1);
    return (unsigned short)(r >> 16);
}
__device__ inline float bf16_to_f32(unsigned short s) {
    return __uint_as_float(((unsigned)s) << 16);
}
__device__ inline float sigmoidf(float x) { return 1.f / (1.f + __expf(-x)); }

// ---------- kernel 1: repack weights (+loop_weight as r=8) to bf16, transposed [r][o][i] ----------
__global__ void k_prep_w(const float* __restrict__ W, const float* __restrict__ LW,
                         unsigned short* __restrict__ Wt) {
    int idx = blockIdx.x * 256 + threadIdx.x;
    if (idx >= 9 * 128 * 128) return;
    int r = idx >> 14;
    int rem = idx & 16383;
    int i = rem >> 7, o = rem & 127;
    float v = (r < 8) ? W[(r << 14) + (i << 7) + o] : LW[(i << 7) + o];
    Wt[(r << 14) + (o << 7) + i] = f32_to_bf16(v);
}

// ---------- kernel 2: gate[r][n] = sigmoid(h[n] . gw[r]) ----------
__global__ void k_gate(const float* __restrict__ h, const float* __restrict__ gw,
                       float* __restrict__ gate) {
    int wave = threadIdx.x >> 6, lane = threadIdx.x & 63;
    int n = blockIdx.x * 4 + wave;
    if (n >= N_NODES) return;
    float2 hv = *(const float2*)(h + (size_t)n * F + lane * 2);
    #pragma unroll
    for (int r = 0; r < 8; ++r) {
        float2 wv = *(const float2*)(gw + r * F + lane * 2);
        float p = hv.x * wv.x + hv.y * wv.y;
        #pragma unroll
        for (int off = 32; off; off >>= 1) p += __shfl_xor(p, off);
        if (lane == 0) gate[r * N_NODES + n] = sigmoidf(p);
    }
}

// ---------- kernel 3: h_rel[r][n][o] = (h @ W_r) in bf16 via MFMA ----------
#define LDH 136
#define LDW 136
__global__ __launch_bounds__(256) void k_hrel(const float* __restrict__ h,
                                              const unsigned short* __restrict__ Wt,
                                              unsigned short* __restrict__ hrel) {
    __shared__ unsigned short hA[64 * LDH];
    __shared__ unsigned short wB[128 * LDW];
    int tid = threadIdx.x;
    int nb = blockIdx.x * 64;

    #pragma unroll
    for (int it = 0; it < 8; ++it) {
        int idx = it * 1024 + tid * 4;
        int row = idx >> 7, col = idx & 127;
        int node = nb + row;
        float4 v;
        if (node < N_NODES) v = *(const float4*)(h + (size_t)node * F + col);
        else                v = make_float4(0.f, 0.f, 0.f, 0.f);
        ushort4 b;
        b.x = f32_to_bf16(v.x); b.y = f32_to_bf16(v.y);
        b.z = f32_to_bf16(v.z); b.w = f32_to_bf16(v.w);
        *(ushort4*)(&hA[row * LDH + col]) = b;
    }

    int wave = tid >> 6, lane = tid & 63;
    int lrow = lane & 15, quad = lane >> 4;
    const unsigned short* aptr = &hA[(wave * 16 + lrow) * LDH + quad * 8];

    for (int r = 0; r < NRELL; ++r) {
        __syncthreads();
        #pragma unroll
        for (int it = 0; it < 8; ++it) {
            int idx = it * 2048 + tid * 8;
            int o = idx >> 7, i = idx & 127;
            *(uint4*)(&wB[o * LDW + i]) = *(const uint4*)(Wt + (r << 14) + idx);
        }
        __syncthreads();

        floatx4 acc[8];
        #pragma unroll
        for (int nt = 0; nt < 8; ++nt) acc[nt] = (floatx4){0.f, 0.f, 0.f, 0.f};
        #pragma unroll
        for (int kt = 0; kt < 4; ++kt) {
            short8 a = *(const short8*)(aptr + kt * 32);
            #pragma unroll
            for (int nt = 0; nt < 8; ++nt) {
                short8 b = *(const short8*)(&wB[(nt * 16 + lrow) * LDW + kt * 32 + quad * 8]);
                acc[nt] = __builtin_amdgcn_mfma_f32_16x16x32_bf16(a, b, acc[nt], 0, 0, 0);
            }
        }
        unsigned short* dstp = hrel + (size_t)r * N_NODES * F;
        #pragma unroll
        for (int nt = 0; nt < 8; ++nt) {
            #pragma unroll
            for (int g = 0; g < 4; ++g) {
                int node = nb + wave * 16 + quad * 4 + g;
                if (node < N_NODES)
                    dstp[(size_t)node * F + nt * 16 + lrow] = f32_to_bf16(acc[nt][g]);
            }
        }
    }
}

// ---------- sort-by-dst machinery ----------
__global__ void k_hist(const int* __restrict__ dst, int* __restrict__ cnt) {
    int e = blockIdx.x * 256 + threadIdx.x;
    if (e < N_EDGES) atomicAdd(&cnt[dst[e]], 1);
}

__global__ void k_scan1(const int* __restrict__ cnt, int* __restrict__ excl,
                        int* __restrict__ bsum) {
    __shared__ int sh[256];
    int g = blockIdx.x * 256 + threadIdx.x;
    int v = (g < N_NODES) ? cnt[g] : 0;
    sh[threadIdx.x] = v;
    __syncthreads();
    #pragma unroll
    for (int off = 1; off < 256; off <<= 1) {
        int t = (threadIdx.x >= off) ? sh[threadIdx.x - off] : 0;
        __syncthreads();
        sh[threadIdx.x] += t;
        __syncthreads();
    }
    if (g < N_NODES) excl[g] = sh[threadIdx.x] - v;
    if (threadIdx.x == 255) bsum[blockIdx.x] = sh[255];
}

__global__ void k_scan2(int* __restrict__ bsum) {
    __shared__ int sh[256];
    int v = (threadIdx.x < NB_SCAN) ? bsum[threadIdx.x] : 0;
    sh[threadIdx.x] = v;
    __syncthreads();
    #pragma unroll
    for (int off = 1; off < 256; off <<= 1) {
        int t = (threadIdx.x >= off) ? sh[threadIdx.x - off] : 0;
        __syncthreads();
        sh[threadIdx.x] += t;
        __syncthreads();
    }
    if (threadIdx.x < NB_SCAN) bsum[threadIdx.x] = sh[threadIdx.x] - v;
}

__global__ void k_scan3(int* __restrict__ excl, const int* __restrict__ bsum,
                        int* __restrict__ cursor) {
    int g = blockIdx.x * 256 + threadIdx.x;
    if (g < N_NODES) {
        int b = excl[g] + bsum[blockIdx.x];
        excl[g] = b;
        cursor[g] = b;
    }
}

__global__ void k_scatter(const int* __restrict__ dst, int* __restrict__ cursor,
                          int* __restrict__ sorted) {
    int e = blockIdx.x * 256 + threadIdx.x;
    if (e < N_EDGES) {
        int pos = atomicAdd(&cursor[dst[e]], 1);
        sorted[pos] = e;
    }
}

// ---------- kernel 4: node-centric gather-reduce, fused epilogue ----------
__global__ __launch_bounds__(256) void k_agg(const unsigned short* __restrict__ hrel,
                      const float* __restrict__ gate,
                      const float* __restrict__ norm,
                      const int* __restrict__ src, const int* __restrict__ rel,
                      const int* __restrict__ sorted,
                      const int* __restrict__ base, const int* __restrict__ cnt,
                      const float* __restrict__ bias,
                      float* __restrict__ out) {
    int wave = threadIdx.x >> 6, lane = threadIdx.x & 63;
    int n = blockIdx.x * 4 + wave;
    if (n >= N_NODES) return;
    int startp = base[n];
    int deg = cnt[n];
    float acc0 = 0.f, acc1 = 0.f;
    for (int c0 = 0; c0 < deg; c0 += 64) {
        int myi = c0 + lane;
        float sc = 0.f;
        int row = 0;
        if (myi < deg) {
            int e = sorted[startp + myi];
            int s = src[e], r = rel[e];
            row = r * N_NODES + s;
            sc = norm[e] * gate[row];
        }
        int lim = (deg - c0 < 64) ? (deg - c0) : 64;
        for (int i = 0; i < lim; ++i) {
            float scl = __shfl(sc, i);
            int rw = __shfl(row, i);
            unsigned m = *(const unsigned*)(hrel + (size_t)rw * F + lane * 2);
            acc0 += scl * bf16_to_f32((unsigned short)(m & 0xffffu));
            acc1 += scl * bf16_to_f32((unsigned short)(m >> 16));
        }
    }
    const unsigned short* hrel8 = hrel + (size_t)8 * N_NODES * F;
    unsigned l8 = *(const unsigned*)(hrel8 + (size_t)n * F + lane * 2);
    float2 bv = *(const float2*)(bias + lane * 2);
    float o0 = fmaxf(acc0 + bv.x + bf16_to_f32((unsigned short)(l8 & 0xffffu)), 0.f);
    float o1 = fmaxf(acc1 + bv.y + bf16_to_f32((unsigned short)(l8 >> 16)), 0.f);
    *(float2*)(out + (size_t)n * F + lane * 2) = make_float2(o0, o1);
}

// ---------- atomic-path kernels (ws mid-size fallback) ----------
__global__ void k_edges(const unsigned short* __restrict__ hrel,
                        const float* __restrict__ gate,
                        const float* __restrict__ norm,
                        const int* __restrict__ src, const int* __restrict__ dst,
                        const int* __restrict__ rel,
                        float* __restrict__ out) {
    int wave = threadIdx.x >> 6, lane = threadIdx.x & 63;
    int e = blockIdx.x * 4 + wave;
    if (e >= N_EDGES) return;
    int s = src[e], d = dst[e], r = rel[e];
    float scale = norm[e] * gate[r * N_NODES + s];
    unsigned int m = *(const unsigned int*)(hrel + ((size_t)r * N_NODES + s) * F + lane * 2);
    float v0 = bf16_to_f32((unsigned short)(m & 0xffffu)) * scale;
    float v1 = bf16_to_f32((unsigned short)(m >> 16)) * scale;
    float* op = out + (size_t)d * F + lane * 2;
    unsafeAtomicAdd(op, v0);
    unsafeAtomicAdd(op + 1, v1);
}

__global__ void k_final(float* __restrict__ out, const float* __restrict__ bias,
                        const unsigned short* __restrict__ hrel8) {
    int idx = blockIdx.x * 256 + threadIdx.x;
    if (idx >= N_NODES * 32) return;
    int node = idx >> 5, c4 = (idx & 31) * 4;
    float4 a = *(float4*)(out + (size_t)node * F + c4);
    float4 b = *(const float4*)(bias + c4);
    ushort4 l = *(const ushort4*)(hrel8 + (size_t)node * F + c4);
    float o0 = fmaxf(a.x + b.x + bf16_to_f32(l.x), 0.f);
    float o1 = fmaxf(a.y + b.y + bf16_to_f32(l.y), 0.f);
    float o2 = fmaxf(a.z + b.z + bf16_to_f32(l.z), 0.f);
    float o3 = fmaxf(a.w + b.w + bf16_to_f32(l.w), 0.f);
    *(float4*)(out + (size_t)node * F + c4) = make_float4(o0, o1, o2, o3);
}

// ---------- ws-free fallback ----------
__global__ void k_edges_fb(const float* __restrict__ h, const float* __restrict__ W,
                           const float* __restrict__ gw, const float* __restrict__ norm,
                           const int* __restrict__ src, const int* __restrict__ dst,
                           const int* __restrict__ rel, float* __restrict__ out) {
    int wave = threadIdx.x >> 6, lane = threadIdx.x & 63;
    int e = blockIdx.x * 4 + wave;
    if (e >= N_EDGES) return;
    int s = src[e], d = dst[e], r = rel[e];
    float2 hv = *(const float2*)(h + (size_t)s * F + lane * 2);
    float2 gv = *(const float2*)(gw + r * F + lane * 2);
    float p = hv.x * gv.x + hv.y * gv.y;
    #pragma unroll
    for (int off = 32; off; off >>= 1) p += __shfl_xor(p, off);
    float scale = norm[e] * sigmoidf(p);
    const float* wr = W + ((size_t)r << 14);
    float a0 = 0.f, a1 = 0.f;
    for (int i2 = 0; i2 < 64; ++i2) {
        float x0 = __shfl(hv.x, i2), x1 = __shfl(hv.y, i2);
        a0 += x0 * wr[(2 * i2) * F + lane]      + x1 * wr[(2 * i2 + 1) * F + lane];
        a1 += x0 * wr[(2 * i2) * F + 64 + lane] + x1 * wr[(2 * i2 + 1) * F + 64 + lane];
    }
    unsafeAtomicAdd(out + (size_t)d * F + lane,      a0 * scale);
    unsafeAtomicAdd(out + (size_t)d * F + 64 + lane, a1 * scale);
}

__global__ void k_final_fb(const float* __restrict__ h, const float* __restrict__ LW,
                           const float* __restrict__ bias, float* __restrict__ out) {
    int wave = threadIdx.x >> 6, lane = threadIdx.x & 63;
    int n = blockIdx.x * 4 + wave;
    if (n >= N_NODES) return;
    float2 hv = *(const float2*)(h + (size_t)n * F + lane * 2);
    float a0 = 0.f, a1 = 0.f;
    for (int i2 = 0; i2 < 64; ++i2) {
        float x0 = __shfl(hv.x, i2), x1 = __shfl(hv.y, i2);
        a0 += x0 * LW[(2 * i2) * F + lane]      + x1 * LW[(2 * i2 + 1) * F + lane];
        a1 += x0 * LW[(2 * i2) * F + 64 + lane] + x1 * LW[(2 * i2 + 1) * F + 64 + lane];
    }
    float* op = out + (size_t)n * F;
    op[lane]      = fmaxf(op[lane]      + bias[lane]      + a0, 0.f);
    op[64 + lane] = fmaxf(op[64 + lane] + bias[64 + lane] + a1, 0.f);
}

extern "C" void kernel_launch(void* const* d_in, const int* in_sizes, int n_in,
                              void* d_out, int out_size, void* d_ws, size_t ws_size,
                              hipStream_t stream) {
    const float* h    = (const float*)d_in[0];
    const float* W    = (const float*)d_in[1];
    const float* gw   = (const float*)d_in[2];
    const float* bias = (const float*)d_in[3];
    const float* lw   = (const float*)d_in[4];
    const float* norm = (const float*)d_in[5];
    const int* src    = (const int*)d_in[6];
    const int* dst    = (const int*)d_in[7];
    const int* rel    = (const int*)d_in[8];
    float* out = (float*)d_out;

    if (ws_size >= WS_NEED2) {
        unsigned short* Wt   = (unsigned short*)d_ws;
        float*          gate = (float*)((char*)d_ws + GATE_OFF);
        unsigned short* hrel = (unsigned short*)((char*)d_ws + HREL_OFF);
        int* cnt    = (int*)((char*)d_ws + CNT_OFF);
        int* base   = (int*)((char*)d_ws + BASE_OFF);
        int* cursor = (int*)((char*)d_ws + CUR_OFF);
        int* bsum   = (int*)((char*)d_ws + BSUM_OFF);
        int* sorted = (int*)((char*)d_ws + SORT_OFF);

        hipMemsetAsync(cnt, 0, N_NODES * sizeof(int), stream);
        k_prep_w<<<576, 256, 0, stream>>>(W, lw, Wt);
        k_gate<<<12500, 256, 0, stream>>>(h, gw, gate);
        k_hist<<<2344, 256, 0, stream>>>(dst, cnt);
        k_scan1<<<NB_SCAN, 256, 0, stream>>>(cnt, base, bsum);
        k_scan2<<<1, 256, 0, stream>>>(bsum);
        k_scan3<<<NB_SCAN, 256, 0, stream>>>(base, bsum, cursor);
        k_scatter<<<2344, 256, 0, stream>>>(dst, cursor, sorted);
        k_hrel<<<782, 256, 0, stream>>>(h, Wt, hrel);
        k_agg<<<12500, 256, 0, stream>>>(hrel, gate, norm, src, rel, sorted,
                                         base, cnt, bias, out);
    } else if (ws_size >= WS_NEED1) {
        unsigned short* Wt   = (unsigned short*)d_ws;
        float*          gate = (float*)((char*)d_ws + GATE_OFF);
        unsigned short* hrel = (unsigned short*)((char*)d_ws + HREL_OFF);
        hipMemsetAsync(d_out, 0, (size_t)out_size * sizeof(float), stream);
        k_prep_w<<<576, 256, 0, stream>>>(W, lw, Wt);
        k_gate<<<12500, 256, 0, stream>>>(h, gw, gate);
        k_hrel<<<782, 256, 0, stream>>>(h, Wt, hrel);
        k_edges<<<150000, 256, 0, stream>>>(hrel, gate, norm, src, dst, rel, out);
        k_final<<<6250, 256, 0, stream>>>(out, bias, hrel + (size_t)8 * N_NODES * F);
    } else {
        hipMemsetAsync(d_out, 0, (size_t)out_size * sizeof(float), stream);
        k_edges_fb<<<150000, 256, 0, stream>>>(h, W, gw, norm, src, dst, rel, out);
        k_final_fb<<<12500, 256, 0, stream>>>(h, lw, bias, out);
    }
}

// Round 3
// 272.124 us; speedup vs baseline: 2.4767x; 1.1112x over previous
//
#include <hip/hip_runtime.h>

#define N_NODES 50000
#define N_EDGES 600000
#define F 128
#define NRELL 9     // 8 relations + self-loop folded in as r=8
#define NB_SCAN 196 // ceil(50000/256)   (round-2 fallback path)
#define NB2 1563    // ceil(400000/256)  (v3 (dst,rel)-bin scan)

// ---------- v3 ws layout (all offsets 16-aligned) ----------
#define WT3_OFF   0                    // 294,912 B  bf16 W [r][o][i-swizzled]
#define H2_OFF    294912               // 12,800,000 B  bf16 h
#define GATE3_OFF 13094912             // 1,600,000 B  sigmoid gates [r][n]
#define CNT3_OFF  14694912             // 1,600,000 B  (dst,rel) histogram; reused as cursor
#define EXCL3_OFF 16294912             // 1,600,256 B  exclusive scan + sentinel
#define BSUM3_OFF 17895168             // 6,400 B
#define REC3_OFF  17901568             // 4,800,000 B  packed {src, scale} per edge
#define A3_OFF    22701568             // 115,310,592 B  bf16 A [n][r][i-swizzled], 50048 rows
#define WS_NEED3  ((size_t)138012160)

// ---------- round-2 fallback ws layout ----------
#define GATE_OFF   294912
#define HREL_OFF   1894912
#define HREL_BYTES (9ll*N_NODES*128*2)
#define CNT_OFF    117094912
#define BASE_OFF   117294912
#define CUR_OFF    117494912
#define BSUM_OFF   117694912
#define SORT_OFF   117695936
#define WS_NEED2   ((size_t)120095936)
#define WS_NEED1   ((size_t)HREL_OFF + (size_t)HREL_BYTES)

typedef __attribute__((ext_vector_type(8))) short short8;
typedef __attribute__((ext_vector_type(4))) float floatx4;

__device__ inline unsigned short f32_to_bf16(float f) {
    unsigned u = __float_as_uint(f);
    unsigned r = u + 0x7fff + ((u >> 16) & 1);
    return (unsigned short)(r >> 16);
}
__device__ inline float bf16_to_f32(unsigned short s) {
    return __uint_as_float(((unsigned)s) << 16);
}
__device__ inline float bf16lo(unsigned m) { return __uint_as_float(m << 16); }
__device__ inline float bf16hi(unsigned m) { return __uint_as_float(m & 0xffff0000u); }
__device__ inline float sigmoidf(float x) { return 1.f / (1.f + __expf(-x)); }

// ---------- shared: pack weights (+loop_weight as r=8) to bf16 [r][o][i], optional granule swizzle ----------
__global__ void k_prep_w(const float* __restrict__ W, const float* __restrict__ LW,
                         unsigned short* __restrict__ Wt, int swz) {
    int idx = blockIdx.x * 256 + threadIdx.x;
    if (idx >= 9 * 128 * 128) return;
    int r = idx >> 14;
    int rem = idx & 16383;
    int i = rem >> 7, o = rem & 127;
    float v = (r < 8) ? W[(r << 14) + (i << 7) + o] : LW[(i << 7) + o];
    int pos;
    if (swz) {
        int g = (i >> 3) ^ (o & 7);               // 16B-granule XOR swizzle keyed on o
        pos = (r << 14) + (o << 7) + (g << 3) + (i & 7);
    } else {
        pos = (r << 14) + (o << 7) + i;
    }
    Wt[pos] = f32_to_bf16(v);
}

// ---------- v3: cast h->bf16 and compute gates, one wave per node ----------
__global__ void k_prep_h(const float* __restrict__ h, const float* __restrict__ gw,
                         unsigned short* __restrict__ h2, float* __restrict__ gate) {
    int wave = threadIdx.x >> 6, lane = threadIdx.x & 63;
    int n = blockIdx.x * 4 + wave;           // grid 12500 -> exactly 50000
    float2 hv = *(const float2*)(h + (size_t)n * F + lane * 2);
    unsigned val = (unsigned)f32_to_bf16(hv.x) | ((unsigned)f32_to_bf16(hv.y) << 16);
    *(unsigned*)(h2 + (size_t)n * F + lane * 2) = val;
    #pragma unroll
    for (int r = 0; r < 8; ++r) {
        float2 wv = *(const float2*)(gw + r * F + lane * 2);
        float p = hv.x * wv.x + hv.y * wv.y;
        #pragma unroll
        for (int off = 32; off; off >>= 1) p += __shfl_xor(p, off);
        if (lane == 0) gate[r * N_NODES + n] = sigmoidf(p);
    }
}

// ---------- v3 sort by (dst,rel): 400000 bins ----------
__global__ void k_hist2(const int* __restrict__ dst, const int* __restrict__ rel,
                        int* __restrict__ cnt) {
    int e = blockIdx.x * 256 + threadIdx.x;
    if (e < N_EDGES) atomicAdd(&cnt[dst[e] * 8 + rel[e]], 1);
}

__global__ void k_s1(const int* __restrict__ cnt, int* __restrict__ excl,
                     int* __restrict__ bsum) {
    __shared__ int sh[256];
    int g = blockIdx.x * 256 + threadIdx.x;
    int v = (g < 400000) ? cnt[g] : 0;
    sh[threadIdx.x] = v;
    __syncthreads();
    #pragma unroll
    for (int off = 1; off < 256; off <<= 1) {
        int t = (threadIdx.x >= off) ? sh[threadIdx.x - off] : 0;
        __syncthreads();
        sh[threadIdx.x] += t;
        __syncthreads();
    }
    if (g < 400000) excl[g] = sh[threadIdx.x] - v;
    if (threadIdx.x == 255) bsum[blockIdx.x] = sh[255];
}

__global__ void k_s2(int* __restrict__ bsum) {   // scan NB2=1563 block sums, 1 block
    __shared__ int sh[256];
    int t = threadIdx.x;
    int v[7];
    int s = 0;
    #pragma unroll
    for (int j = 0; j < 7; ++j) {
        int idx = t * 7 + j;
        v[j] = (idx < NB2) ? bsum[idx] : 0;
        s += v[j];
    }
    sh[t] = s;
    __syncthreads();
    #pragma unroll
    for (int off = 1; off < 256; off <<= 1) {
        int tt = (t >= off) ? sh[t - off] : 0;
        __syncthreads();
        sh[t] += tt;
        __syncthreads();
    }
    int run = sh[t] - s;
    #pragma unroll
    for (int j = 0; j < 7; ++j) {
        int idx = t * 7 + j;
        if (idx < NB2) bsum[idx] = run;
        run += v[j];
    }
}

__global__ void k_s3(int* __restrict__ excl, const int* __restrict__ bsum,
                     int* __restrict__ cursor) {
    int g = blockIdx.x * 256 + threadIdx.x;
    if (g < 400000) {
        int b = excl[g] + bsum[blockIdx.x];
        excl[g] = b;
        cursor[g] = b;
    }
    if (g == 0) excl[400000] = N_EDGES;   // sentinel
}

__global__ void k_scatter2(const int* __restrict__ src, const int* __restrict__ dst,
                           const int* __restrict__ rel, const float* __restrict__ norm,
                           const float* __restrict__ gate, int* __restrict__ cursor,
                           int2* __restrict__ rec) {
    int e = blockIdx.x * 256 + threadIdx.x;
    if (e >= N_EDGES) return;
    int d = dst[e], r = rel[e], s = src[e];
    int pos = atomicAdd(&cursor[d * 8 + r], 1);
    float sc = norm[e] * gate[r * N_NODES + s];
    rec[pos] = make_int2(s, __float_as_int(sc));
}

// ---------- v3: per-node input-space aggregation -> A [n][9][128] bf16 (swizzled) ----------
__global__ __launch_bounds__(256) void k_aggA(const unsigned short* __restrict__ h2,
                                              const int2* __restrict__ rec,
                                              const int* __restrict__ excl,
                                              unsigned short* __restrict__ A) {
    int wave = threadIdx.x >> 6, lane = threadIdx.x & 63;
    int n = blockIdx.x * 4 + wave;            // grid 12500 -> exactly 50000
    int ex = 0;
    if (lane < 9) ex = excl[n * 8 + lane];
    int e0 = __shfl(ex, 0), e8 = __shfl(ex, 8);
    int deg = e8 - e0;
    unsigned short* Arow = A + (size_t)n * 1152;
    int swo = (((lane >> 2) ^ (n & 7)) << 2) + (lane & 3);  // swizzled uint slot in 256B seg

    if (deg <= 64) {
        int rs = 0; float rsc = 0.f;
        if (lane < deg) {
            int2 rc = rec[e0 + lane];
            rs = rc.x; rsc = __int_as_float(rc.y);
        }
        for (int r = 0; r < 8; ++r) {
            int s = __shfl(ex, r) - e0;
            int e = __shfl(ex, r + 1) - e0;
            float a0 = 0.f, a1 = 0.f;
            for (int j = s; j < e; ++j) {
                int sj = __shfl(rs, j);
                float sc = __shfl(rsc, j);
                unsigned m = *(const unsigned*)(h2 + (size_t)sj * F + lane * 2);
                a0 += sc * bf16lo(m);
                a1 += sc * bf16hi(m);
            }
            unsigned val = (unsigned)f32_to_bf16(a0) | ((unsigned)f32_to_bf16(a1) << 16);
            ((unsigned*)(Arow + r * 128))[swo] = val;
        }
    } else {   // safety path for high-degree nodes
        for (int r = 0; r < 8; ++r) {
            int s = __shfl(ex, r);
            int e = __shfl(ex, r + 1);
            float a0 = 0.f, a1 = 0.f;
            for (int idx = s; idx < e; ++idx) {
                int2 rc = rec[idx];                       // wave-uniform broadcast load
                float sc = __int_as_float(rc.y);
                unsigned m = *(const unsigned*)(h2 + (size_t)rc.x * F + lane * 2);
                a0 += sc * bf16lo(m);
                a1 += sc * bf16hi(m);
            }
            unsigned val = (unsigned)f32_to_bf16(a0) | ((unsigned)f32_to_bf16(a1) << 16);
            ((unsigned*)(Arow + r * 128))[swo] = val;
        }
    }
    // r=8 self-loop: copy h2 row (already bf16)
    unsigned hm = ((const unsigned*)(h2 + (size_t)n * F))[lane];
    ((unsigned*)(Arow + 8 * 128))[swo] = hm;
}

// ---------- v3: out = relu(A @ W + bias), M=50000 K=1152 N=128 ----------
__global__ __launch_bounds__(256) void k_gemmA(const unsigned short* __restrict__ A,
                                               const unsigned short* __restrict__ Wt,
                                               const float* __restrict__ bias,
                                               float* __restrict__ out) {
    __shared__ unsigned short sA[16384];   // 128 rows x 128 k (swizzled granules)
    __shared__ unsigned short sB[16384];   // 128 o   x 128 k (swizzled granules)
    int tid = threadIdx.x;
    int nb = blockIdx.x * 128;
    int wave = tid >> 6, lane = tid & 63, lrow = lane & 15, quad = lane >> 4;

    floatx4 acc[2][8];
    #pragma unroll
    for (int mt = 0; mt < 2; ++mt)
        #pragma unroll
        for (int nt = 0; nt < 8; ++nt) acc[mt][nt] = (floatx4){0.f, 0.f, 0.f, 0.f};

    for (int kb = 0; kb < 9; ++kb) {
        __syncthreads();
        #pragma unroll
        for (int it = 0; it < 8; ++it) {
            int g = it * 256 + tid;          // granule 0..2047
            int row = g >> 4, gr = g & 15;
            *(uint4*)(&sA[row * 128 + gr * 8]) =
                *(const uint4*)(A + (size_t)(nb + row) * 1152 + kb * 128 + gr * 8);
            *(uint4*)(&sB[row * 128 + gr * 8]) =
                *(const uint4*)(Wt + (kb << 14) + (g << 3));
        }
        __syncthreads();
        #pragma unroll
        for (int kt = 0; kt < 4; ++kt) {
            int j = kt * 4 + quad;
            int sw = (j ^ (lrow & 7)) << 3;
            short8 a0 = *(const short8*)(&sA[(wave * 32 + lrow) * 128 + sw]);
            short8 a1 = *(const short8*)(&sA[(wave * 32 + 16 + lrow) * 128 + sw]);
            #pragma unroll
            for (int nt = 0; nt < 8; ++nt) {
                short8 b = *(const short8*)(&sB[(nt * 16 + lrow) * 128 + sw]);
                acc[0][nt] = __builtin_amdgcn_mfma_f32_16x16x32_bf16(a0, b, acc[0][nt], 0, 0, 0);
                acc[1][nt] = __builtin_amdgcn_mfma_f32_16x16x32_bf16(a1, b, acc[1][nt], 0, 0, 0);
            }
        }
    }
    #pragma unroll
    for (int mt = 0; mt < 2; ++mt) {
        #pragma unroll
        for (int nt = 0; nt < 8; ++nt) {
            int col = nt * 16 + lrow;
            float bv = bias[col];
            #pragma unroll
            for (int g = 0; g < 4; ++g) {
                int row = nb + wave * 32 + mt * 16 + quad * 4 + g;
                if (row < N_NODES)
                    out[(size_t)row * F + col] = fmaxf(acc[mt][nt][g] + bv, 0.f);
            }
        }
    }
}

// ================= round-2 fallback path kernels =================
__global__ void k_gate(const float* __restrict__ h, const float* __restrict__ gw,
                       float* __restrict__ gate) {
    int wave = threadIdx.x >> 6, lane = threadIdx.x & 63;
    int n = blockIdx.x * 4 + wave;
    if (n >= N_NODES) return;
    float2 hv = *(const float2*)(h + (size_t)n * F + lane * 2);
    #pragma unroll
    for (int r = 0; r < 8; ++r) {
        float2 wv = *(const float2*)(gw + r * F + lane * 2);
        float p = hv.x * wv.x + hv.y * wv.y;
        #pragma unroll
        for (int off = 32; off; off >>= 1) p += __shfl_xor(p, off);
        if (lane == 0) gate[r * N_NODES + n] = sigmoidf(p);
    }
}

#define LDH 136
#define LDW 136
__global__ __launch_bounds__(256) void k_hrel(const float* __restrict__ h,
                                              const unsigned short* __restrict__ Wt,
                                              unsigned short* __restrict__ hrel) {
    __shared__ unsigned short hA[64 * LDH];
    __shared__ unsigned short wB[128 * LDW];
    int tid = threadIdx.x;
    int nb = blockIdx.x * 64;
    #pragma unroll
    for (int it = 0; it < 8; ++it) {
        int idx = it * 1024 + tid * 4;
        int row = idx >> 7, col = idx & 127;
        int node = nb + row;
        float4 v;
        if (node < N_NODES) v = *(const float4*)(h + (size_t)node * F + col);
        else                v = make_float4(0.f, 0.f, 0.f, 0.f);
        ushort4 b;
        b.x = f32_to_bf16(v.x); b.y = f32_to_bf16(v.y);
        b.z = f32_to_bf16(v.z); b.w = f32_to_bf16(v.w);
        *(ushort4*)(&hA[row * LDH + col]) = b;
    }
    int wave = tid >> 6, lane = tid & 63;
    int lrow = lane & 15, quad = lane >> 4;
    const unsigned short* aptr = &hA[(wave * 16 + lrow) * LDH + quad * 8];
    for (int r = 0; r < NRELL; ++r) {
        __syncthreads();
        #pragma unroll
        for (int it = 0; it < 8; ++it) {
            int idx = it * 2048 + tid * 8;
            int o = idx >> 7, i = idx & 127;
            *(uint4*)(&wB[o * LDW + i]) = *(const uint4*)(Wt + (r << 14) + idx);
        }
        __syncthreads();
        floatx4 acc[8];
        #pragma unroll
        for (int nt = 0; nt < 8; ++nt) acc[nt] = (floatx4){0.f, 0.f, 0.f, 0.f};
        #pragma unroll
        for (int kt = 0; kt < 4; ++kt) {
            short8 a = *(const short8*)(aptr + kt * 32);
            #pragma unroll
            for (int nt = 0; nt < 8; ++nt) {
                short8 b = *(const short8*)(&wB[(nt * 16 + lrow) * LDW + kt * 32 + quad * 8]);
                acc[nt] = __builtin_amdgcn_mfma_f32_16x16x32_bf16(a, b, acc[nt], 0, 0, 0);
            }
        }
        unsigned short* dstp = hrel + (size_t)r * N_NODES * F;
        #pragma unroll
        for (int nt = 0; nt < 8; ++nt) {
            #pragma unroll
            for (int g = 0; g < 4; ++g) {
                int node = nb + wave * 16 + quad * 4 + g;
                if (node < N_NODES)
                    dstp[(size_t)node * F + nt * 16 + lrow] = f32_to_bf16(acc[nt][g]);
            }
        }
    }
}

__global__ void k_hist(const int* __restrict__ dst, int* __restrict__ cnt) {
    int e = blockIdx.x * 256 + threadIdx.x;
    if (e < N_EDGES) atomicAdd(&cnt[dst[e]], 1);
}

__global__ void k_scan1(const int* __restrict__ cnt, int* __restrict__ excl,
                        int* __restrict__ bsum) {
    __shared__ int sh[256];
    int g = blockIdx.x * 256 + threadIdx.x;
    int v = (g < N_NODES) ? cnt[g] : 0;
    sh[threadIdx.x] = v;
    __syncthreads();
    #pragma unroll
    for (int off = 1; off < 256; off <<= 1) {
        int t = (threadIdx.x >= off) ? sh[threadIdx.x - off] : 0;
        __syncthreads();
        sh[threadIdx.x] += t;
        __syncthreads();
    }
    if (g < N_NODES) excl[g] = sh[threadIdx.x] - v;
    if (threadIdx.x == 255) bsum[blockIdx.x] = sh[255];
}

__global__ void k_scan2(int* __restrict__ bsum) {
    __shared__ int sh[256];
    int v = (threadIdx.x < NB_SCAN) ? bsum[threadIdx.x] : 0;
    sh[threadIdx.x] = v;
    __syncthreads();
    #pragma unroll
    for (int off = 1; off < 256; off <<= 1) {
        int t = (threadIdx.x >= off) ? sh[threadIdx.x - off] : 0;
        __syncthreads();
        sh[threadIdx.x] += t;
        __syncthreads();
    }
    if (threadIdx.x < NB_SCAN) bsum[threadIdx.x] = sh[threadIdx.x] - v;
}

__global__ void k_scan3(int* __restrict__ excl, const int* __restrict__ bsum,
                        int* __restrict__ cursor) {
    int g = blockIdx.x * 256 + threadIdx.x;
    if (g < N_NODES) {
        int b = excl[g] + bsum[blockIdx.x];
        excl[g] = b;
        cursor[g] = b;
    }
}

__global__ void k_scatter(const int* __restrict__ dst, int* __restrict__ cursor,
                          int* __restrict__ sorted) {
    int e = blockIdx.x * 256 + threadIdx.x;
    if (e < N_EDGES) {
        int pos = atomicAdd(&cursor[dst[e]], 1);
        sorted[pos] = e;
    }
}

__global__ __launch_bounds__(256) void k_agg(const unsigned short* __restrict__ hrel,
                      const float* __restrict__ gate,
                      const float* __restrict__ norm,
                      const int* __restrict__ src, const int* __restrict__ rel,
                      const int* __restrict__ sorted,
                      const int* __restrict__ base, const int* __restrict__ cnt,
                      const float* __restrict__ bias,
                      float* __restrict__ out) {
    int wave = threadIdx.x >> 6, lane = threadIdx.x & 63;
    int n = blockIdx.x * 4 + wave;
    if (n >= N_NODES) return;
    int startp = base[n];
    int deg = cnt[n];
    float acc0 = 0.f, acc1 = 0.f;
    for (int c0 = 0; c0 < deg; c0 += 64) {
        int myi = c0 + lane;
        float sc = 0.f;
        int row = 0;
        if (myi < deg) {
            int e = sorted[startp + myi];
            int s = src[e], r = rel[e];
            row = r * N_NODES + s;
            sc = norm[e] * gate[row];
        }
        int lim = (deg - c0 < 64) ? (deg - c0) : 64;
        for (int i = 0; i < lim; ++i) {
            float scl = __shfl(sc, i);
            int rw = __shfl(row, i);
            unsigned m = *(const unsigned*)(hrel + (size_t)rw * F + lane * 2);
            acc0 += scl * bf16lo(m);
            acc1 += scl * bf16hi(m);
        }
    }
    const unsigned short* hrel8 = hrel + (size_t)8 * N_NODES * F;
    unsigned l8 = *(const unsigned*)(hrel8 + (size_t)n * F + lane * 2);
    float2 bv = *(const float2*)(bias + lane * 2);
    float o0 = fmaxf(acc0 + bv.x + bf16lo(l8), 0.f);
    float o1 = fmaxf(acc1 + bv.y + bf16hi(l8), 0.f);
    *(float2*)(out + (size_t)n * F + lane * 2) = make_float2(o0, o1);
}

__global__ void k_edges(const unsigned short* __restrict__ hrel,
                        const float* __restrict__ gate,
                        const float* __restrict__ norm,
                        const int* __restrict__ src, const int* __restrict__ dst,
                        const int* __restrict__ rel,
                        float* __restrict__ out) {
    int wave = threadIdx.x >> 6, lane = threadIdx.x & 63;
    int e = blockIdx.x * 4 + wave;
    if (e >= N_EDGES) return;
    int s = src[e], d = dst[e], r = rel[e];
    float scale = norm[e] * gate[r * N_NODES + s];
    unsigned int m = *(const unsigned int*)(hrel + ((size_t)r * N_NODES + s) * F + lane * 2);
    float v0 = bf16lo(m) * scale;
    float v1 = bf16hi(m) * scale;
    float* op = out + (size_t)d * F + lane * 2;
    unsafeAtomicAdd(op, v0);
    unsafeAtomicAdd(op + 1, v1);
}

__global__ void k_final(float* __restrict__ out, const float* __restrict__ bias,
                        const unsigned short* __restrict__ hrel8) {
    int idx = blockIdx.x * 256 + threadIdx.x;
    if (idx >= N_NODES * 32) return;
    int node = idx >> 5, c4 = (idx & 31) * 4;
    float4 a = *(float4*)(out + (size_t)node * F + c4);
    float4 b = *(const float4*)(bias + c4);
    ushort4 l = *(const ushort4*)(hrel8 + (size_t)node * F + c4);
    float o0 = fmaxf(a.x + b.x + bf16_to_f32(l.x), 0.f);
    float o1 = fmaxf(a.y + b.y + bf16_to_f32(l.y), 0.f);
    float o2 = fmaxf(a.z + b.z + bf16_to_f32(l.z), 0.f);
    float o3 = fmaxf(a.w + b.w + bf16_to_f32(l.w), 0.f);
    *(float4*)(out + (size_t)node * F + c4) = make_float4(o0, o1, o2, o3);
}

__global__ void k_edges_fb(const float* __restrict__ h, const float* __restrict__ W,
                           const float* __restrict__ gw, const float* __restrict__ norm,
                           const int* __restrict__ src, const int* __restrict__ dst,
                           const int* __restrict__ rel, float* __restrict__ out) {
    int wave = threadIdx.x >> 6, lane = threadIdx.x & 63;
    int e = blockIdx.x * 4 + wave;
    if (e >= N_EDGES) return;
    int s = src[e], d = dst[e], r = rel[e];
    float2 hv = *(const float2*)(h + (size_t)s * F + lane * 2);
    float2 gv = *(const float2*)(gw + r * F + lane * 2);
    float p = hv.x * gv.x + hv.y * gv.y;
    #pragma unroll
    for (int off = 32; off; off >>= 1) p += __shfl_xor(p, off);
    float scale = norm[e] * sigmoidf(p);
    const float* wr = W + ((size_t)r << 14);
    float a0 = 0.f, a1 = 0.f;
    for (int i2 = 0; i2 < 64; ++i2) {
        float x0 = __shfl(hv.x, i2), x1 = __shfl(hv.y, i2);
        a0 += x0 * wr[(2 * i2) * F + lane]      + x1 * wr[(2 * i2 + 1) * F + lane];
        a1 += x0 * wr[(2 * i2) * F + 64 + lane] + x1 * wr[(2 * i2 + 1) * F + 64 + lane];
    }
    unsafeAtomicAdd(out + (size_t)d * F + lane,      a0 * scale);
    unsafeAtomicAdd(out + (size_t)d * F + 64 + lane, a1 * scale);
}

__global__ void k_final_fb(const float* __restrict__ h, const float* __restrict__ LW,
                           const float* __restrict__ bias, float* __restrict__ out) {
    int wave = threadIdx.x >> 6, lane = threadIdx.x & 63;
    int n = blockIdx.x * 4 + wave;
    if (n >= N_NODES) return;
    float2 hv = *(const float2*)(h + (size_t)n * F + lane * 2);
    float a0 = 0.f, a1 = 0.f;
    for (int i2 = 0; i2 < 64; ++i2) {
        float x0 = __shfl(hv.x, i2), x1 = __shfl(hv.y, i2);
        a0 += x0 * LW[(2 * i2) * F + lane]      + x1 * LW[(2 * i2 + 1) * F + lane];
        a1 += x0 * LW[(2 * i2) * F + 64 + lane] + x1 * LW[(2 * i2 + 1) * F + 64 + lane];
    }
    float* op = out + (size_t)n * F;
    op[lane]      = fmaxf(op[lane]      + bias[lane]      + a0, 0.f);
    op[64 + lane] = fmaxf(op[64 + lane] + bias[64 + lane] + a1, 0.f);
}

extern "C" void kernel_launch(void* const* d_in, const int* in_sizes, int n_in,
                              void* d_out, int out_size, void* d_ws, size_t ws_size,
                              hipStream_t stream) {
    const float* h    = (const float*)d_in[0];
    const float* W    = (const float*)d_in[1];
    const float* gw   = (const float*)d_in[2];
    const float* bias = (const float*)d_in[3];
    const float* lw   = (const float*)d_in[4];
    const float* norm = (const float*)d_in[5];
    const int* src    = (const int*)d_in[6];
    const int* dst    = (const int*)d_in[7];
    const int* rel    = (const int*)d_in[8];
    float* out = (float*)d_out;

    if (ws_size >= WS_NEED3) {
        unsigned short* Wt   = (unsigned short*)((char*)d_ws + WT3_OFF);
        unsigned short* h2   = (unsigned short*)((char*)d_ws + H2_OFF);
        float*          gate = (float*)((char*)d_ws + GATE3_OFF);
        int*            cnt  = (int*)((char*)d_ws + CNT3_OFF);   // reused as cursor
        int*            excl = (int*)((char*)d_ws + EXCL3_OFF);
        int*            bsum = (int*)((char*)d_ws + BSUM3_OFF);
        int2*           rec  = (int2*)((char*)d_ws + REC3_OFF);
        unsigned short* A    = (unsigned short*)((char*)d_ws + A3_OFF);

        hipMemsetAsync(cnt, 0, 400000 * sizeof(int), stream);
        k_prep_w<<<576, 256, 0, stream>>>(W, lw, Wt, 1);
        k_prep_h<<<12500, 256, 0, stream>>>(h, gw, h2, gate);
        k_hist2<<<2344, 256, 0, stream>>>(dst, rel, cnt);
        k_s1<<<NB2, 256, 0, stream>>>(cnt, excl, bsum);
        k_s2<<<1, 256, 0, stream>>>(bsum);
        k_s3<<<NB2, 256, 0, stream>>>(excl, bsum, cnt);
        k_scatter2<<<2344, 256, 0, stream>>>(src, dst, rel, norm, gate, cnt, rec);
        k_aggA<<<12500, 256, 0, stream>>>(h2, rec, excl, A);
        k_gemmA<<<391, 256, 0, stream>>>(A, Wt, bias, out);
    } else if (ws_size >= WS_NEED2) {
        unsigned short* Wt   = (unsigned short*)d_ws;
        float*          gate = (float*)((char*)d_ws + GATE_OFF);
        unsigned short* hrel = (unsigned short*)((char*)d_ws + HREL_OFF);
        int* cnt    = (int*)((char*)d_ws + CNT_OFF);
        int* base   = (int*)((char*)d_ws + BASE_OFF);
        int* cursor = (int*)((char*)d_ws + CUR_OFF);
        int* bsum   = (int*)((char*)d_ws + BSUM_OFF);
        int* sorted = (int*)((char*)d_ws + SORT_OFF);
        hipMemsetAsync(cnt, 0, N_NODES * sizeof(int), stream);
        k_prep_w<<<576, 256, 0, stream>>>(W, lw, Wt, 0);
        k_gate<<<12500, 256, 0, stream>>>(h, gw, gate);
        k_hist<<<2344, 256, 0, stream>>>(dst, cnt);
        k_scan1<<<NB_SCAN, 256, 0, stream>>>(cnt, base, bsum);
        k_scan2<<<1, 256, 0, stream>>>(bsum);
        k_scan3<<<NB_SCAN, 256, 0, stream>>>(base, bsum, cursor);
        k_scatter<<<2344, 256, 0, stream>>>(dst, cursor, sorted);
        k_hrel<<<782, 256, 0, stream>>>(h, Wt, hrel);
        k_agg<<<12500, 256, 0, stream>>>(hrel, gate, norm, src, rel, sorted,
                                         base, cnt, bias, out);
    } else if (ws_size >= WS_NEED1) {
        unsigned short* Wt   = (unsigned short*)d_ws;
        float*          gate = (float*)((char*)d_ws + GATE_OFF);
        unsigned short* hrel = (unsigned short*)((char*)d_ws + HREL_OFF);
        hipMemsetAsync(d_out, 0, (size_t)out_size * sizeof(float), stream);
        k_prep_w<<<576, 256, 0, stream>>>(W, lw, Wt, 0);
        k_gate<<<12500, 256, 0, stream>>>(h, gw, gate);
        k_hrel<<<782, 256, 0, stream>>>(h, Wt, hrel);
        k_edges<<<150000, 256, 0, stream>>>(hrel, gate, norm, src, dst, rel, out);
        k_final<<<6250, 256, 0, stream>>>(out, bias, hrel + (size_t)8 * N_NODES * F);
    } else {
        hipMemsetAsync(d_out, 0, (size_t)out_size * sizeof(float), stream);
        k_edges_fb<<<150000, 256, 0, stream>>>(h, W, gw, norm, src, dst, rel, out);
        k_final_fb<<<12500, 256, 0, stream>>>(h, lw, bias, out);
    }
}